// Round 15
// baseline (621.805 us; speedup 1.0000x reference)
//
#include <hip/hip_runtime.h>
#include <cstdint>

#define NN 4096
#define EE 131072
#define BB 64
#define EPAD (EE + 8 * NN)   // CSR rows padded to multiples of 8

typedef float f4 __attribute__((ext_vector_type(4)));
typedef short bf16x8 __attribute__((ext_vector_type(8)));
typedef unsigned int u4 __attribute__((ext_vector_type(4)));
typedef unsigned int u2 __attribute__((ext_vector_type(2)));
typedef unsigned short ushort_t;
typedef unsigned int uint_t;

// bf16 helpers
__device__ __forceinline__ void up8(u4 u, f4& lo, f4& hi) {
    lo.x = __uint_as_float(u.x << 16);
    lo.y = __uint_as_float(u.x & 0xffff0000u);
    lo.z = __uint_as_float(u.y << 16);
    lo.w = __uint_as_float(u.y & 0xffff0000u);
    hi.x = __uint_as_float(u.z << 16);
    hi.y = __uint_as_float(u.z & 0xffff0000u);
    hi.z = __uint_as_float(u.w << 16);
    hi.w = __uint_as_float(u.w & 0xffff0000u);
}
__device__ __forceinline__ uint_t bfpk(float a, float b) {
    uint_t xa = __float_as_uint(a); xa = (xa + 0x7fffu + ((xa >> 16) & 1u)) >> 16;
    uint_t xb = __float_as_uint(b); xb = (xb + 0x7fffu + ((xb >> 16) & 1u));
    return (xa & 0xffffu) | (xb & 0xffff0000u);
}

// PERMUTED wide layout (per 512-col chunk): storage s(b,c) = 8b + 128*(c>>3) + (c&7)
// for local batch b in [0,16), channel c in [0,32). Element-wise kernels
// (spmm_pure) are layout-transparent; cheb gathers at lane*8 and the 8 loaded
// elements ARE the MFMA data fragment (b = lane&15, ci = (lane>>4)*8 + j).

// ---------------------------------------------------------------------------
// Graph preprocessing
// ---------------------------------------------------------------------------
__global__ void k_deg_hist(const int* __restrict__ src, const int* __restrict__ dst,
                           const float* __restrict__ ew, float* __restrict__ deg,
                           int* __restrict__ cnt) {
    int e = blockIdx.x * blockDim.x + threadIdx.x;
    if (e >= EE) return;
    atomicAdd(&deg[src[e]], ew[e]);
    atomicAdd(&cnt[dst[e]], 1);
}

__global__ __launch_bounds__(1024) void k_scan(const int* __restrict__ cnt,
                                               int* __restrict__ rowptr,
                                               int* __restrict__ cursor) {
    __shared__ int s[1024];
    int tid = threadIdx.x;
    int p0 = (cnt[tid * 4 + 0] + 7) & ~7;
    int p1 = (cnt[tid * 4 + 1] + 7) & ~7;
    int p2 = (cnt[tid * 4 + 2] + 7) & ~7;
    int p3 = (cnt[tid * 4 + 3] + 7) & ~7;
    int sum = p0 + p1 + p2 + p3;
    s[tid] = sum;
    __syncthreads();
    for (int off = 1; off < 1024; off <<= 1) {
        int t = (tid >= off) ? s[tid - off] : 0;
        __syncthreads();
        s[tid] += t;
        __syncthreads();
    }
    int excl = s[tid] - sum;
    rowptr[tid * 4 + 0] = excl; cursor[tid * 4 + 0] = excl; excl += p0;
    rowptr[tid * 4 + 1] = excl; cursor[tid * 4 + 1] = excl; excl += p1;
    rowptr[tid * 4 + 2] = excl; cursor[tid * 4 + 2] = excl; excl += p2;
    rowptr[tid * 4 + 3] = excl; cursor[tid * 4 + 3] = excl; excl += p3;
    if (tid == 1023) rowptr[4096] = excl;
}

__global__ void k_fill(const int* __restrict__ src, const int* __restrict__ dst,
                       const float* __restrict__ ew, const float* __restrict__ deg,
                       int* __restrict__ cursor, int2* __restrict__ cv) {
    int e = blockIdx.x * blockDim.x + threadIdx.x;
    if (e >= EE) return;
    int s = src[e], d = dst[e];
    int pos = atomicAdd(&cursor[d], 1);
    float ds = deg[s], dd = deg[d];
    float is = ds > 0.f ? rsqrtf(fmaxf(ds, 1e-30f)) : 0.f;
    float id = dd > 0.f ? rsqrtf(fmaxf(dd, 1e-30f)) : 0.f;
    float v = -(is * ew[e] * id);
    cv[pos] = make_int2(s, __float_as_int(v));
}

// ---------------------------------------------------------------------------
// Degree-balanced scheduling permutation (counting sort, DESCENDING degree):
// bucket = 63 - min(63, paddeg>>3). Heavy rows first; the 4 waves of each
// block get near-equal iteration counts; drain tail is light rows.
// ---------------------------------------------------------------------------
__global__ __launch_bounds__(256) void k_deg_buckets(const int* __restrict__ rowptr,
                                                     int* __restrict__ bcnt) {
    int n = blockIdx.x * 256 + threadIdx.x;
    if (n >= NN) return;
    int d = (rowptr[n + 1] - rowptr[n]) >> 3;
    int b = d > 63 ? 63 : d;
    atomicAdd(&bcnt[63 - b], 1);
}

__global__ __launch_bounds__(64) void k_scan_buckets(const int* __restrict__ bcnt,
                                                     int* __restrict__ bcur) {
    __shared__ int s[64];
    int tid = threadIdx.x;
    int v = bcnt[tid];
    s[tid] = v;
    __syncthreads();
    for (int off = 1; off < 64; off <<= 1) {
        int t = (tid >= off) ? s[tid - off] : 0;
        __syncthreads();
        s[tid] += t;
        __syncthreads();
    }
    bcur[tid] = s[tid] - v;   // exclusive prefix
}

__global__ __launch_bounds__(256) void k_scatter_perm(const int* __restrict__ rowptr,
                                                      int* __restrict__ bcur,
                                                      int* __restrict__ perm) {
    int n = blockIdx.x * 256 + threadIdx.x;
    if (n >= NN) return;
    int d = (rowptr[n + 1] - rowptr[n]) >> 3;
    int b = d > 63 ? 63 : d;
    int pos = atomicAdd(&bcur[63 - b], 1);
    perm[pos] = n;
}

// ---------------------------------------------------------------------------
// One-time weight pre-pack into MFMA fragment order (bf16 pairs):
// Wb[L][kk*512 + co*16 + u] = (W_L[kk][2u][co], W_L[kk][2u+1][co])
// ---------------------------------------------------------------------------
__global__ __launch_bounds__(256) void k_packw(const float* __restrict__ w2,
                                               const float* __restrict__ w3,
                                               const float* __restrict__ w4,
                                               const float* __restrict__ w5,
                                               uint_t* __restrict__ Wb) {
    int idx = blockIdx.x * 256 + threadIdx.x;  // 0..8191
    int L = idx >> 11, rem = idx & 2047;
    int kk = rem >> 9, r2 = rem & 511, co = r2 >> 4, u = r2 & 15;
    float lo, hi;
    if (L < 3) {
        const float* W = (L == 0) ? w2 : (L == 1) ? w3 : w4;
        lo = W[kk * 1024 + (2 * u) * 32 + co];
        hi = W[kk * 1024 + (2 * u + 1) * 32 + co];
    } else {
        lo = (co < 4) ? w5[kk * 128 + (2 * u) * 4 + co] : 0.f;
        hi = (co < 4) ? w5[kk * 128 + (2 * u + 1) * 4 + co] : 0.f;
    }
    Wb[idx] = bfpk(lo, hi);
}

// ---------------------------------------------------------------------------
// Transpose x [B,N] -> X0 [N,B]  (fp32, layer-1 narrow path)
// ---------------------------------------------------------------------------
__global__ __launch_bounds__(256) void k_transpose_x(const float* __restrict__ x,
                                                     float* __restrict__ X0) {
    __shared__ float s[64 * 65];
    int n0 = blockIdx.x * 64;
    for (int idx = threadIdx.x; idx < 4096; idx += 256) {
        int b = idx >> 6, nl = idx & 63;
        s[nl * 65 + b] = x[(size_t)b * NN + n0 + nl];
    }
    __syncthreads();
    for (int idx = threadIdx.x; idx < 4096; idx += 256) {
        int nl = idx >> 6, b = idx & 63;
        X0[(size_t)(n0 + nl) * 64 + b] = s[nl * 65 + b];
    }
}

// ---------------------------------------------------------------------------
// SpMM narrow (width 64, fp32, layer 1), tail-free x8 gather loop, perm'd
// ---------------------------------------------------------------------------
__global__ __launch_bounds__(64) void k_spmm_narrow(const int* __restrict__ rowptr,
                                                    const int2* __restrict__ cv,
                                                    const int* __restrict__ perm,
                                                    const float* __restrict__ Zin,
                                                    const float* __restrict__ Tprev,
                                                    float* __restrict__ Tout,
                                                    float alpha, int useprev) {
    int n = perm[blockIdx.x];
    int lane = threadIdx.x;
    int start = rowptr[n], end = rowptr[n + 1];
    float acc = 0.f;
    for (int e = start; e < end; e += 8) {
        const int4* q = reinterpret_cast<const int4*>(cv + e);
        int4 a = q[0], b = q[1], c = q[2], d = q[3];
        float z0 = Zin[((size_t)a.x << 6) + lane];
        float z1 = Zin[((size_t)a.z << 6) + lane];
        float z2 = Zin[((size_t)b.x << 6) + lane];
        float z3 = Zin[((size_t)b.z << 6) + lane];
        float z4 = Zin[((size_t)c.x << 6) + lane];
        float z5 = Zin[((size_t)c.z << 6) + lane];
        float z6 = Zin[((size_t)d.x << 6) + lane];
        float z7 = Zin[((size_t)d.z << 6) + lane];
        acc += __int_as_float(a.y) * z0 + __int_as_float(a.w) * z1
             + __int_as_float(b.y) * z2 + __int_as_float(b.w) * z3
             + __int_as_float(c.y) * z4 + __int_as_float(c.w) * z5
             + __int_as_float(d.y) * z6 + __int_as_float(d.w) * z7;
    }
    size_t o = ((size_t)n << 6) + lane;
    float r = alpha * acc;
    if (useprev) r -= Tprev[o];
    Tout[o] = r;
}

// ---------------------------------------------------------------------------
// Layer-1 expand -> bf16 H, PERMUTED layout.
// ---------------------------------------------------------------------------
__global__ __launch_bounds__(256) void k_expand1(const float* __restrict__ T0,
                                                 const float* __restrict__ T1,
                                                 const float* __restrict__ T2,
                                                 const float* __restrict__ T3,
                                                 const float* __restrict__ w1,
                                                 const float* __restrict__ b1,
                                                 ushort_t* __restrict__ H) {
    __shared__ float sT[4][64];
    __shared__ float sW[128];
    __shared__ float sB[32];
    int n = blockIdx.x, tid = threadIdx.x;
    {
        int k = tid >> 6, b = tid & 63;
        const float* Tk = (k == 0) ? T0 : (k == 1) ? T1 : (k == 2) ? T2 : T3;
        sT[k][b] = Tk[(size_t)n * 64 + b];
    }
    if (tid < 128) sW[tid] = w1[tid];
    if (tid < 32) sB[tid] = b1[tid];
    __syncthreads();
    int chunk = tid >> 6, blk = tid & 63;
    int b_g = chunk * 16 + (blk & 15);
    int co0 = (blk >> 4) * 8;
    float t0 = sT[0][b_g], t1 = sT[1][b_g], t2 = sT[2][b_g], t3 = sT[3][b_g];
    float r[8];
#pragma unroll
    for (int j = 0; j < 8; ++j) {
        int co = co0 + j;
        float v = t0 * sW[co] + t1 * sW[32 + co] + t2 * sW[64 + co] + t3 * sW[96 + co] + sB[co];
        r[j] = v > 0.f ? v : 0.f;
    }
    u4 st;
    st.x = bfpk(r[0], r[1]); st.y = bfpk(r[2], r[3]);
    st.z = bfpk(r[4], r[5]); st.w = bfpk(r[6], r[7]);
    *reinterpret_cast<u4*>(H + (size_t)n * 2048 + tid * 8) = st;
}

// ---------------------------------------------------------------------------
// Pure wide SpMM (bf16, fp32 accumulate), 4 chunks x 512 cols, 16B gathers.
// Rows processed via degree-balanced perm.
// ---------------------------------------------------------------------------
__global__ __launch_bounds__(256, 4) void k_spmm_pure(const int* __restrict__ rowptr,
                                                      const int2* __restrict__ cv,
                                                      const int* __restrict__ perm,
                                                      const ushort_t* __restrict__ Zg,
                                                      const ushort_t* __restrict__ Pown,
                                                      ushort_t* __restrict__ Tout) {
    int chunk = blockIdx.x & 3;
    int rowblk = blockIdx.x >> 2;
    int wave = threadIdx.x >> 6;
    int lane = threadIdx.x & 63;
    int n = perm[rowblk * 4 + wave];
    int col0 = chunk * 512 + lane * 8;

    int start = rowptr[n], end = rowptr[n + 1];
    f4 aL0 = {0,0,0,0}, aH0 = {0,0,0,0}, aL1 = {0,0,0,0}, aH1 = {0,0,0,0};
    for (int e = start; e < end; e += 8) {
        const int4* q = reinterpret_cast<const int4*>(cv + e);
        int4 a = q[0], b = q[1], c = q[2], d = q[3];
        u4 u0 = *reinterpret_cast<const u4*>(Zg + (((size_t)a.x) << 11) + col0);
        u4 u1 = *reinterpret_cast<const u4*>(Zg + (((size_t)a.z) << 11) + col0);
        u4 u2 = *reinterpret_cast<const u4*>(Zg + (((size_t)b.x) << 11) + col0);
        u4 u3 = *reinterpret_cast<const u4*>(Zg + (((size_t)b.z) << 11) + col0);
        u4 u4_ = *reinterpret_cast<const u4*>(Zg + (((size_t)c.x) << 11) + col0);
        u4 u5 = *reinterpret_cast<const u4*>(Zg + (((size_t)c.z) << 11) + col0);
        u4 u6 = *reinterpret_cast<const u4*>(Zg + (((size_t)d.x) << 11) + col0);
        u4 u7 = *reinterpret_cast<const u4*>(Zg + (((size_t)d.z) << 11) + col0);
        f4 lo, hi;
        up8(u0, lo, hi);  aL0 += __int_as_float(a.y) * lo; aH0 += __int_as_float(a.y) * hi;
        up8(u1, lo, hi);  aL1 += __int_as_float(a.w) * lo; aH1 += __int_as_float(a.w) * hi;
        up8(u2, lo, hi);  aL0 += __int_as_float(b.y) * lo; aH0 += __int_as_float(b.y) * hi;
        up8(u3, lo, hi);  aL1 += __int_as_float(b.w) * lo; aH1 += __int_as_float(b.w) * hi;
        up8(u4_, lo, hi); aL0 += __int_as_float(c.y) * lo; aH0 += __int_as_float(c.y) * hi;
        up8(u5, lo, hi);  aL1 += __int_as_float(c.w) * lo; aH1 += __int_as_float(c.w) * hi;
        up8(u6, lo, hi);  aL0 += __int_as_float(d.y) * lo; aH0 += __int_as_float(d.y) * hi;
        up8(u7, lo, hi);  aL1 += __int_as_float(d.w) * lo; aH1 += __int_as_float(d.w) * hi;
    }
    size_t o = (((size_t)n) << 11) + col0;
    f4 tL = aL0 + aL1, tH = aH0 + aH1;
    if (Pown) {
        u4 pu = *reinterpret_cast<const u4*>(Pown + o);
        f4 pL, pH;
        up8(pu, pL, pH);
        tL = 2.f * tL - pL;
        tH = 2.f * tH - pH;
    }
    u4 st;
    st.x = bfpk(tL.x, tL.y); st.y = bfpk(tL.z, tL.w);
    st.z = bfpk(tH.x, tH.y); st.w = bfpk(tH.z, tH.w);
    *reinterpret_cast<u4*>(Tout + o) = st;
}

// ---------------------------------------------------------------------------
// Chebyshev finalizer, register-direct MFMA, PERMUTED layout + perm'd rows.
// ---------------------------------------------------------------------------
template <int COUT>
__global__ __launch_bounds__(256, 4) void k_cheb_mfma(
    const int* __restrict__ rowptr, const int2* __restrict__ cv,
    const int* __restrict__ perm,
    const ushort_t* __restrict__ T2g,  // gather source (T2), also own-row read
    const ushort_t* __restrict__ T1,   // own-row: Pown + W1 operand
    const ushort_t* __restrict__ H,    // own-row: W0 operand
    const uint_t* __restrict__ Wb,     // [4][32co][16] bf16-pair fragments
    const float* __restrict__ bias,    // [COUT]
    void* __restrict__ OUTv)
{
    int chunk = blockIdx.x & 3;
    int rowblk = blockIdx.x >> 2;
    int wave = threadIdx.x >> 6;
    int lane = threadIdx.x & 63;
    int n = perm[rowblk * 4 + wave];
    int b16 = lane & 15, qk = lane >> 4;
    int col0 = chunk * 512 + lane * 8;
    size_t o = (((size_t)n) << 11) + col0;

    // hoisted own-row loads: latency overlaps the gather loop
    u4 a1 = *reinterpret_cast<const u4*>(T1 + o);
    u4 a2 = *reinterpret_cast<const u4*>(T2g + o);
    u4 a0 = *reinterpret_cast<const u4*>(H + o);

    int start = rowptr[n], end = rowptr[n + 1];
    f4 aL0 = {0,0,0,0}, aH0 = {0,0,0,0}, aL1 = {0,0,0,0}, aH1 = {0,0,0,0};
    for (int e = start; e < end; e += 8) {
        const int4* q = reinterpret_cast<const int4*>(cv + e);
        int4 a = q[0], b = q[1], c = q[2], d = q[3];
        u4 u0 = *reinterpret_cast<const u4*>(T2g + (((size_t)a.x) << 11) + col0);
        u4 u1 = *reinterpret_cast<const u4*>(T2g + (((size_t)a.z) << 11) + col0);
        u4 u2 = *reinterpret_cast<const u4*>(T2g + (((size_t)b.x) << 11) + col0);
        u4 u3 = *reinterpret_cast<const u4*>(T2g + (((size_t)b.z) << 11) + col0);
        u4 u4_ = *reinterpret_cast<const u4*>(T2g + (((size_t)c.x) << 11) + col0);
        u4 u5 = *reinterpret_cast<const u4*>(T2g + (((size_t)c.z) << 11) + col0);
        u4 u6 = *reinterpret_cast<const u4*>(T2g + (((size_t)d.x) << 11) + col0);
        u4 u7 = *reinterpret_cast<const u4*>(T2g + (((size_t)d.z) << 11) + col0);
        f4 lo, hi;
        up8(u0, lo, hi);  aL0 += __int_as_float(a.y) * lo; aH0 += __int_as_float(a.y) * hi;
        up8(u1, lo, hi);  aL1 += __int_as_float(a.w) * lo; aH1 += __int_as_float(a.w) * hi;
        up8(u2, lo, hi);  aL0 += __int_as_float(b.y) * lo; aH0 += __int_as_float(b.y) * hi;
        up8(u3, lo, hi);  aL1 += __int_as_float(b.w) * lo; aH1 += __int_as_float(b.w) * hi;
        up8(u4_, lo, hi); aL0 += __int_as_float(c.y) * lo; aH0 += __int_as_float(c.y) * hi;
        up8(u5, lo, hi);  aL1 += __int_as_float(c.w) * lo; aH1 += __int_as_float(c.w) * hi;
        up8(u6, lo, hi);  aL0 += __int_as_float(d.y) * lo; aH0 += __int_as_float(d.y) * hi;
        up8(u7, lo, hi);  aL1 += __int_as_float(d.w) * lo; aH1 += __int_as_float(d.w) * hi;
    }

    // T3 = 2*(L@T2) - T1 (bf16-packed, same permuted fragment positions)
    u4 a3;
    {
        f4 pL, pH;
        up8(a1, pL, pH);
        f4 tL = 2.f * (aL0 + aL1) - pL;
        f4 tH = 2.f * (aH0 + aH1) - pH;
        a3.x = bfpk(tL.x, tL.y); a3.y = bfpk(tL.z, tL.w);
        a3.z = bfpk(tH.x, tH.y); a3.w = bfpk(tH.z, tH.w);
    }

    // A-fragments (weights) from pre-packed global (L2-hot, 8KB)
    const uint_t* wb = Wb + b16 * 16 + qk * 4;
    f4 accA = {0,0,0,0}, accB = {0,0,0,0};
#pragma unroll
    for (int kk = 0; kk < 4; ++kk) {
        u4 af4 = (kk == 0) ? a0 : (kk == 1) ? a1 : (kk == 2) ? a2 : a3;
        bf16x8 bf_data = *reinterpret_cast<bf16x8*>(&af4);
        u4 w0 = *reinterpret_cast<const u4*>(wb + kk * 512);
        bf16x8 af_w0 = *reinterpret_cast<bf16x8*>(&w0);
        accA = __builtin_amdgcn_mfma_f32_16x16x32_bf16(af_w0, bf_data, accA, 0, 0, 0);
        if constexpr (COUT == 32) {
            u4 w1 = *reinterpret_cast<const u4*>(wb + kk * 512 + 256);
            bf16x8 af_w1 = *reinterpret_cast<bf16x8*>(&w1);
            accB = __builtin_amdgcn_mfma_f32_16x16x32_bf16(af_w1, bf_data, accB, 0, 0, 0);
        }
    }

    if constexpr (COUT == 32) {
        f4 bA = *reinterpret_cast<const f4*>(bias + qk * 4);
        f4 bB = *reinterpret_cast<const f4*>(bias + 16 + qk * 4);
        f4 vA = accA + bA, vB = accB + bB;
        vA.x = vA.x > 0.f ? vA.x : 0.f; vA.y = vA.y > 0.f ? vA.y : 0.f;
        vA.z = vA.z > 0.f ? vA.z : 0.f; vA.w = vA.w > 0.f ? vA.w : 0.f;
        vB.x = vB.x > 0.f ? vB.x : 0.f; vB.y = vB.y > 0.f ? vB.y : 0.f;
        vB.z = vB.z > 0.f ? vB.z : 0.f; vB.w = vB.w > 0.f ? vB.w : 0.f;
        ushort_t* OB = (ushort_t*)OUTv;
        int sA = 8 * b16 + ((qk >> 1) << 7) + ((qk & 1) << 2);
        size_t obase = (((size_t)n) << 11) + chunk * 512;
        u2 pA, pB;
        pA.x = bfpk(vA.x, vA.y); pA.y = bfpk(vA.z, vA.w);
        pB.x = bfpk(vB.x, vB.y); pB.y = bfpk(vB.z, vB.w);
        *reinterpret_cast<u2*>(OB + obase + sA) = pA;
        *reinterpret_cast<u2*>(OB + obase + sA + 256) = pB;
    } else {  // COUT == 4: logical fp32 out [N][256]; qk==0 holds co 0..3
        if (qk == 0) {
            f4 bA = *reinterpret_cast<const f4*>(bias);
            f4 vA = accA + bA;
            vA.x = vA.x > 0.f ? vA.x : 0.f; vA.y = vA.y > 0.f ? vA.y : 0.f;
            vA.z = vA.z > 0.f ? vA.z : 0.f; vA.w = vA.w > 0.f ? vA.w : 0.f;
            float* OF = (float*)OUTv;
            *reinterpret_cast<f4*>(OF + (size_t)n * 256 + chunk * 64 + b16 * 4) = vA;
        }
    }
}

// ---------------------------------------------------------------------------
// FC1: split-K over 128 blocks, atomic accumulate. h[b, n*4+c] = H5[n, b*4+c]
// ---------------------------------------------------------------------------
__global__ __launch_bounds__(256) void k_fc1(const float* __restrict__ H5,
                                             const float* __restrict__ fw1,
                                             float* __restrict__ fc1out) {
    __shared__ float hT[128 * 65];
    __shared__ float wS[32 * 128];
    int tid = threadIdx.x;
    int n0 = blockIdx.x * 32;
    for (int idx = tid; idx < 8192; idx += 256) {
        int n_l = idx >> 8;
        int rem = idx & 255;
        int b = rem >> 2, c = rem & 3;
        int kk = n_l * 4 + c;
        hT[kk * 65 + b] = H5[(size_t)(n0 + n_l) * 256 + rem];
    }
    float acc[8][4];
#pragma unroll
    for (int i = 0; i < 8; ++i)
#pragma unroll
        for (int j = 0; j < 4; ++j) acc[i][j] = 0.f;
    int bq = tid >> 5;
    int jq = tid & 31;
    for (int kb = 0; kb < 128; kb += 32) {
        __syncthreads();
        for (int idx = tid; idx < 4096; idx += 256) {
            int kl = idx >> 7, j = idx & 127;
            wS[idx] = fw1[(size_t)(n0 * 4 + kb + kl) * 128 + j];
        }
        __syncthreads();
        for (int kl = 0; kl < 32; ++kl) {
            int kk = kb + kl;
            float4 w = *reinterpret_cast<const float4*>(&wS[kl * 128 + jq * 4]);
#pragma unroll
            for (int bi = 0; bi < 8; ++bi) {
                float h = hT[kk * 65 + bq * 8 + bi];
                acc[bi][0] += h * w.x;
                acc[bi][1] += h * w.y;
                acc[bi][2] += h * w.z;
                acc[bi][3] += h * w.w;
            }
        }
    }
#pragma unroll
    for (int bi = 0; bi < 8; ++bi)
#pragma unroll
        for (int ji = 0; ji < 4; ++ji)
            atomicAdd(&fc1out[(bq * 8 + bi) * 128 + jq * 4 + ji], acc[bi][ji]);
}

__global__ __launch_bounds__(128) void k_fc23(const float* __restrict__ fc1out,
                                              const float* __restrict__ fb1,
                                              const float* __restrict__ fw2,
                                              const float* __restrict__ fb2,
                                              const float* __restrict__ fw3,
                                              const float* __restrict__ fb3,
                                              float* __restrict__ out) {
    int b = blockIdx.x;
    int j = threadIdx.x;
    __shared__ float r[128];
    __shared__ float s1[128];
    r[j] = fc1out[b * 128 + j] + fb1[j];
    __syncthreads();
    float acc = fb2[j];
    for (int i = 0; i < 128; ++i) acc += r[i] * fw2[i * 128 + j];
    s1[j] = acc;
    __syncthreads();
    if (j < 9) {
        float a2 = fb3[j];
        for (int i = 0; i < 128; ++i) a2 += s1[i] * fw3[i * 9 + j];
        out[b * 9 + j] = a2;
    }
}

// ---------------------------------------------------------------------------
extern "C" void kernel_launch(void* const* d_in, const int* in_sizes, int n_in,
                              void* d_out, int out_size, void* d_ws, size_t ws_size,
                              hipStream_t stream) {
    const float* x   = (const float*)d_in[0];
    const int*   src = (const int*)d_in[1];
    const int*   dst = (const int*)d_in[2];
    const float* ew  = (const float*)d_in[3];
    const float* w1  = (const float*)d_in[4];
    const float* b1  = (const float*)d_in[5];
    const float* w2  = (const float*)d_in[6];
    const float* b2  = (const float*)d_in[7];
    const float* w3  = (const float*)d_in[8];
    const float* b3  = (const float*)d_in[9];
    const float* w4  = (const float*)d_in[10];
    const float* b4  = (const float*)d_in[11];
    const float* w5  = (const float*)d_in[12];
    const float* b5  = (const float*)d_in[13];
    const float* fw1 = (const float*)d_in[14];
    const float* fb1 = (const float*)d_in[15];
    const float* fw2 = (const float*)d_in[16];
    const float* fb2 = (const float*)d_in[17];
    const float* fw3 = (const float*)d_in[18];
    const float* fb3 = (const float*)d_in[19];
    float* out = (float*)d_out;

    char* p = (char*)d_ws;
    const size_t XBYTES = (size_t)NN * 2048 * 2;  // 16 MB (bf16)
    ushort_t* X0 = (ushort_t*)(p + 0 * XBYTES);
    ushort_t* X1 = (ushort_t*)(p + 1 * XBYTES);
    ushort_t* X2 = (ushort_t*)(p + 2 * XBYTES);
    ushort_t* X3 = (ushort_t*)(p + 3 * XBYTES);
    size_t off = 4 * XBYTES;
    float* H5     = (float*)(p + off); off += (size_t)NN * 256 * 4;  // fp32
    float* deg    = (float*)(p + off); off += (size_t)NN * 4;
    int*   cnt    = (int*)(p + off);   off += (size_t)NN * 4;
    int*   cursor = (int*)(p + off);   off += (size_t)NN * 4;
    int*   rowptr = (int*)(p + off);   off += (size_t)(NN + 4) * 4;
    int2*  cv     = (int2*)(p + off);  off += (size_t)EPAD * 8;
    float* fc1o   = (float*)(p + off); off += (size_t)BB * 128 * 4;
    float* xn0    = (float*)(p + off); off += (size_t)NN * 64 * 4;
    float* tn1    = (float*)(p + off); off += (size_t)NN * 64 * 4;
    float* tn2    = (float*)(p + off); off += (size_t)NN * 64 * 4;
    float* tn3    = (float*)(p + off); off += (size_t)NN * 64 * 4;
    uint_t* Wb    = (uint_t*)(p + off); off += (size_t)4 * 2048 * 4;
    int*   bcnt   = (int*)(p + off);   off += 64 * 4;
    int*   bcur   = (int*)(p + off);   off += 64 * 4;
    int*   perm   = (int*)(p + off);   off += (size_t)NN * 4;
    if (off > ws_size) return;

    hipMemsetAsync(deg, 0, NN * 4, stream);
    hipMemsetAsync(cnt, 0, NN * 4, stream);
    hipMemsetAsync(cv, 0, (size_t)EPAD * 8, stream);
    hipMemsetAsync(fc1o, 0, BB * 128 * 4, stream);
    hipMemsetAsync(bcnt, 0, 64 * 4, stream);

    k_deg_hist<<<EE / 256, 256, 0, stream>>>(src, dst, ew, deg, cnt);
    k_scan<<<1, 1024, 0, stream>>>(cnt, rowptr, cursor);
    k_fill<<<EE / 256, 256, 0, stream>>>(src, dst, ew, deg, cursor, cv);
    k_deg_buckets<<<NN / 256, 256, 0, stream>>>(rowptr, bcnt);
    k_scan_buckets<<<1, 64, 0, stream>>>(bcnt, bcur);
    k_scatter_perm<<<NN / 256, 256, 0, stream>>>(rowptr, bcur, perm);
    k_packw<<<32, 256, 0, stream>>>(w2, w3, w4, w5, Wb);
    k_transpose_x<<<NN / 64, 256, 0, stream>>>(x, xn0);

    // ------------------- layer 1 entirely narrow fp32, then one bf16 expand
    k_spmm_narrow<<<NN, 64, 0, stream>>>(rowptr, cv, perm, xn0, nullptr, tn1, 1.f, 0);
    k_spmm_narrow<<<NN, 64, 0, stream>>>(rowptr, cv, perm, tn1, xn0, tn2, 2.f, 1);
    k_spmm_narrow<<<NN, 64, 0, stream>>>(rowptr, cv, perm, tn2, tn1, tn3, 2.f, 1);
    k_expand1<<<NN, 256, 0, stream>>>(xn0, tn1, tn2, tn3, w1, b1, X3);  // H1 -> X3

    const int GRID4 = (NN / 4) * 4;   // 4096 blocks: 4 chunks x 512 cols
    // ------------------- layers 2-4: S1, S2 pure; S3 fused MFMA finalizer
    auto run32 = [&](const ushort_t* H, ushort_t* T1, ushort_t* T2, ushort_t* OUT,
                     const uint_t* WbL, const float* B) {
        k_spmm_pure<<<GRID4, 256, 0, stream>>>(rowptr, cv, perm, H, nullptr, T1);
        k_spmm_pure<<<GRID4, 256, 0, stream>>>(rowptr, cv, perm, T1, H, T2);
        k_cheb_mfma<32><<<GRID4, 256, 0, stream>>>(rowptr, cv, perm, T2, T1, H, WbL, B, OUT);
    };
    run32(X3, X0, X1, X2, Wb + 0 * 2048, b2);
    run32(X2, X3, X0, X1, Wb + 1 * 2048, b3);
    run32(X1, X2, X3, X0, Wb + 2 * 2048, b4);

    // ------------------- layer 5 (COUT=4): H=X0 -> H5 fp32 [N][256]
    k_spmm_pure<<<GRID4, 256, 0, stream>>>(rowptr, cv, perm, X0, nullptr, X1);
    k_spmm_pure<<<GRID4, 256, 0, stream>>>(rowptr, cv, perm, X1, X0, X2);
    k_cheb_mfma<4><<<GRID4, 256, 0, stream>>>(rowptr, cv, perm, X2, X1, X0, Wb + 3 * 2048, b5, H5);

    // ------------------- FC head
    k_fc1<<<128, 256, 0, stream>>>(H5, fw1, fc1o);
    k_fc23<<<BB, 128, 0, stream>>>(fc1o, fb1, fw2, fb2, fw3, fb3, out);
}

// Round 16
// 589.183 us; speedup vs baseline: 1.0554x; 1.0554x over previous
//
#include <hip/hip_runtime.h>
#include <cstdint>

#define NN 4096
#define EE 131072
#define BB 64
#define EPAD (EE + 8 * NN)   // CSR rows padded to multiples of 8 (+8 zero edges at end)

typedef float f4 __attribute__((ext_vector_type(4)));
typedef short bf16x8 __attribute__((ext_vector_type(8)));
typedef unsigned int u4 __attribute__((ext_vector_type(4)));
typedef unsigned int u2 __attribute__((ext_vector_type(2)));
typedef unsigned short ushort_t;
typedef unsigned int uint_t;

// bf16 helpers
__device__ __forceinline__ void up8(u4 u, f4& lo, f4& hi) {
    lo.x = __uint_as_float(u.x << 16);
    lo.y = __uint_as_float(u.x & 0xffff0000u);
    lo.z = __uint_as_float(u.y << 16);
    lo.w = __uint_as_float(u.y & 0xffff0000u);
    hi.x = __uint_as_float(u.z << 16);
    hi.y = __uint_as_float(u.z & 0xffff0000u);
    hi.z = __uint_as_float(u.w << 16);
    hi.w = __uint_as_float(u.w & 0xffff0000u);
}
__device__ __forceinline__ uint_t bfpk(float a, float b) {
    uint_t xa = __float_as_uint(a); xa = (xa + 0x7fffu + ((xa >> 16) & 1u)) >> 16;
    uint_t xb = __float_as_uint(b); xb = (xb + 0x7fffu + ((xb >> 16) & 1u));
    return (xa & 0xffffu) | (xb & 0xffff0000u);
}

// PERMUTED wide layout (per 512-col chunk): storage s(b,c) = 8b + 128*(c>>3) + (c&7)
// for local batch b in [0,16), channel c in [0,32). Element-wise kernels
// (spmm_pure) are layout-transparent; cheb gathers at lane*8 and the 8 loaded
// elements ARE the MFMA data fragment (b = lane&15, ci = (lane>>4)*8 + j).

// ---------------------------------------------------------------------------
// Graph preprocessing
// ---------------------------------------------------------------------------
__global__ void k_deg_hist(const int* __restrict__ src, const int* __restrict__ dst,
                           const float* __restrict__ ew, float* __restrict__ deg,
                           int* __restrict__ cnt) {
    int e = blockIdx.x * blockDim.x + threadIdx.x;
    if (e >= EE) return;
    atomicAdd(&deg[src[e]], ew[e]);
    atomicAdd(&cnt[dst[e]], 1);
}

__global__ __launch_bounds__(1024) void k_scan(const int* __restrict__ cnt,
                                               int* __restrict__ rowptr,
                                               int* __restrict__ cursor) {
    __shared__ int s[1024];
    int tid = threadIdx.x;
    int p0 = (cnt[tid * 4 + 0] + 7) & ~7;
    int p1 = (cnt[tid * 4 + 1] + 7) & ~7;
    int p2 = (cnt[tid * 4 + 2] + 7) & ~7;
    int p3 = (cnt[tid * 4 + 3] + 7) & ~7;
    int sum = p0 + p1 + p2 + p3;
    s[tid] = sum;
    __syncthreads();
    for (int off = 1; off < 1024; off <<= 1) {
        int t = (tid >= off) ? s[tid - off] : 0;
        __syncthreads();
        s[tid] += t;
        __syncthreads();
    }
    int excl = s[tid] - sum;
    rowptr[tid * 4 + 0] = excl; cursor[tid * 4 + 0] = excl; excl += p0;
    rowptr[tid * 4 + 1] = excl; cursor[tid * 4 + 1] = excl; excl += p1;
    rowptr[tid * 4 + 2] = excl; cursor[tid * 4 + 2] = excl; excl += p2;
    rowptr[tid * 4 + 3] = excl; cursor[tid * 4 + 3] = excl; excl += p3;
    if (tid == 1023) rowptr[4096] = excl;
}

__global__ void k_fill(const int* __restrict__ src, const int* __restrict__ dst,
                       const float* __restrict__ ew, const float* __restrict__ deg,
                       int* __restrict__ cursor, int2* __restrict__ cv) {
    int e = blockIdx.x * blockDim.x + threadIdx.x;
    if (e >= EE) return;
    int s = src[e], d = dst[e];
    int pos = atomicAdd(&cursor[d], 1);
    float ds = deg[s], dd = deg[d];
    float is = ds > 0.f ? rsqrtf(fmaxf(ds, 1e-30f)) : 0.f;
    float id = dd > 0.f ? rsqrtf(fmaxf(dd, 1e-30f)) : 0.f;
    float v = -(is * ew[e] * id);
    cv[pos] = make_int2(s, __float_as_int(v));
}

// ---------------------------------------------------------------------------
// One-time weight pre-pack into MFMA fragment order (bf16 pairs):
// Wb[L][kk*512 + co*16 + u] = (W_L[kk][2u][co], W_L[kk][2u+1][co])
// ---------------------------------------------------------------------------
__global__ __launch_bounds__(256) void k_packw(const float* __restrict__ w2,
                                               const float* __restrict__ w3,
                                               const float* __restrict__ w4,
                                               const float* __restrict__ w5,
                                               uint_t* __restrict__ Wb) {
    int idx = blockIdx.x * 256 + threadIdx.x;  // 0..8191
    int L = idx >> 11, rem = idx & 2047;
    int kk = rem >> 9, r2 = rem & 511, co = r2 >> 4, u = r2 & 15;
    float lo, hi;
    if (L < 3) {
        const float* W = (L == 0) ? w2 : (L == 1) ? w3 : w4;
        lo = W[kk * 1024 + (2 * u) * 32 + co];
        hi = W[kk * 1024 + (2 * u + 1) * 32 + co];
    } else {
        lo = (co < 4) ? w5[kk * 128 + (2 * u) * 4 + co] : 0.f;
        hi = (co < 4) ? w5[kk * 128 + (2 * u + 1) * 4 + co] : 0.f;
    }
    Wb[idx] = bfpk(lo, hi);
}

// ---------------------------------------------------------------------------
// Transpose x [B,N] -> X0 [N,B]  (fp32, layer-1 narrow path)
// ---------------------------------------------------------------------------
__global__ __launch_bounds__(256) void k_transpose_x(const float* __restrict__ x,
                                                     float* __restrict__ X0) {
    __shared__ float s[64 * 65];
    int n0 = blockIdx.x * 64;
    for (int idx = threadIdx.x; idx < 4096; idx += 256) {
        int b = idx >> 6, nl = idx & 63;
        s[nl * 65 + b] = x[(size_t)b * NN + n0 + nl];
    }
    __syncthreads();
    for (int idx = threadIdx.x; idx < 4096; idx += 256) {
        int nl = idx >> 6, b = idx & 63;
        X0[(size_t)(n0 + nl) * 64 + b] = s[nl * 65 + b];
    }
}

// ---------------------------------------------------------------------------
// SpMM narrow (width 64, fp32, layer 1), tail-free x8 gather loop
// ---------------------------------------------------------------------------
__global__ __launch_bounds__(64) void k_spmm_narrow(const int* __restrict__ rowptr,
                                                    const int2* __restrict__ cv,
                                                    const float* __restrict__ Zin,
                                                    const float* __restrict__ Tprev,
                                                    float* __restrict__ Tout,
                                                    float alpha, int useprev) {
    int n = blockIdx.x;
    int lane = threadIdx.x;
    int start = rowptr[n], end = rowptr[n + 1];
    float acc = 0.f;
    for (int e = start; e < end; e += 8) {
        const int4* q = reinterpret_cast<const int4*>(cv + e);
        int4 a = q[0], b = q[1], c = q[2], d = q[3];
        float z0 = Zin[((size_t)a.x << 6) + lane];
        float z1 = Zin[((size_t)a.z << 6) + lane];
        float z2 = Zin[((size_t)b.x << 6) + lane];
        float z3 = Zin[((size_t)b.z << 6) + lane];
        float z4 = Zin[((size_t)c.x << 6) + lane];
        float z5 = Zin[((size_t)c.z << 6) + lane];
        float z6 = Zin[((size_t)d.x << 6) + lane];
        float z7 = Zin[((size_t)d.z << 6) + lane];
        acc += __int_as_float(a.y) * z0 + __int_as_float(a.w) * z1
             + __int_as_float(b.y) * z2 + __int_as_float(b.w) * z3
             + __int_as_float(c.y) * z4 + __int_as_float(c.w) * z5
             + __int_as_float(d.y) * z6 + __int_as_float(d.w) * z7;
    }
    size_t o = ((size_t)n << 6) + lane;
    float r = alpha * acc;
    if (useprev) r -= Tprev[o];
    Tout[o] = r;
}

// ---------------------------------------------------------------------------
// Layer-1 expand -> bf16 H, PERMUTED layout.
// ---------------------------------------------------------------------------
__global__ __launch_bounds__(256) void k_expand1(const float* __restrict__ T0,
                                                 const float* __restrict__ T1,
                                                 const float* __restrict__ T2,
                                                 const float* __restrict__ T3,
                                                 const float* __restrict__ w1,
                                                 const float* __restrict__ b1,
                                                 ushort_t* __restrict__ H) {
    __shared__ float sT[4][64];
    __shared__ float sW[128];
    __shared__ float sB[32];
    int n = blockIdx.x, tid = threadIdx.x;
    {
        int k = tid >> 6, b = tid & 63;
        const float* Tk = (k == 0) ? T0 : (k == 1) ? T1 : (k == 2) ? T2 : T3;
        sT[k][b] = Tk[(size_t)n * 64 + b];
    }
    if (tid < 128) sW[tid] = w1[tid];
    if (tid < 32) sB[tid] = b1[tid];
    __syncthreads();
    int chunk = tid >> 6, blk = tid & 63;
    int b_g = chunk * 16 + (blk & 15);
    int co0 = (blk >> 4) * 8;
    float t0 = sT[0][b_g], t1 = sT[1][b_g], t2 = sT[2][b_g], t3 = sT[3][b_g];
    float r[8];
#pragma unroll
    for (int j = 0; j < 8; ++j) {
        int co = co0 + j;
        float v = t0 * sW[co] + t1 * sW[32 + co] + t2 * sW[64 + co] + t3 * sW[96 + co] + sB[co];
        r[j] = v > 0.f ? v : 0.f;
    }
    u4 st;
    st.x = bfpk(r[0], r[1]); st.y = bfpk(r[2], r[3]);
    st.z = bfpk(r[4], r[5]); st.w = bfpk(r[6], r[7]);
    *reinterpret_cast<u4*>(H + (size_t)n * 2048 + tid * 8) = st;
}

// ---------------------------------------------------------------------------
// Pure wide SpMM (bf16, fp32 accumulate), 4 chunks x 512 cols, 16B gathers.
// TWO rows per wave (nA, nA+4), branch-free interleaved loop: exhausted row
// reads the reserved all-zero edge group at cv[EPAD] (FMA x0). ~24 independent
// loads in flight per iteration (2x MLP vs one-row version).
// ---------------------------------------------------------------------------
__global__ __launch_bounds__(256, 3) void k_spmm_pure(const int* __restrict__ rowptr,
                                                      const int2* __restrict__ cv,
                                                      const ushort_t* __restrict__ Zg,
                                                      const ushort_t* __restrict__ Pown,
                                                      ushort_t* __restrict__ Tout) {
    int chunk = blockIdx.x & 3;
    int rowblk = blockIdx.x >> 2;
    int wave = threadIdx.x >> 6;
    int lane = threadIdx.x & 63;
    int nA = rowblk * 8 + wave;
    int nB = nA + 4;
    int col0 = chunk * 512 + lane * 8;

    int sA = rowptr[nA], itA = (rowptr[nA + 1] - sA) >> 3;
    int sB = rowptr[nB], itB = (rowptr[nB + 1] - sB) >> 3;
    int itmax = itA > itB ? itA : itB;

    f4 aL0 = {0,0,0,0}, aH0 = {0,0,0,0}, aL1 = {0,0,0,0}, aH1 = {0,0,0,0};
    f4 bL0 = {0,0,0,0}, bH0 = {0,0,0,0}, bL1 = {0,0,0,0}, bH1 = {0,0,0,0};
    for (int i = 0; i < itmax; ++i) {
        int eA = (i < itA) ? (sA + i * 8) : EPAD;  // EPAD: zero group
        int eB = (i < itB) ? (sB + i * 8) : EPAD;
        const int4* qa = reinterpret_cast<const int4*>(cv + eA);
        const int4* qb = reinterpret_cast<const int4*>(cv + eB);
        int4 a0 = qa[0], a1 = qa[1], a2 = qa[2], a3 = qa[3];
        int4 b0 = qb[0], b1 = qb[1], b2 = qb[2], b3 = qb[3];
        u4 uA0 = *reinterpret_cast<const u4*>(Zg + (((size_t)a0.x) << 11) + col0);
        u4 uA1 = *reinterpret_cast<const u4*>(Zg + (((size_t)a0.z) << 11) + col0);
        u4 uA2 = *reinterpret_cast<const u4*>(Zg + (((size_t)a1.x) << 11) + col0);
        u4 uA3 = *reinterpret_cast<const u4*>(Zg + (((size_t)a1.z) << 11) + col0);
        u4 uA4 = *reinterpret_cast<const u4*>(Zg + (((size_t)a2.x) << 11) + col0);
        u4 uA5 = *reinterpret_cast<const u4*>(Zg + (((size_t)a2.z) << 11) + col0);
        u4 uA6 = *reinterpret_cast<const u4*>(Zg + (((size_t)a3.x) << 11) + col0);
        u4 uA7 = *reinterpret_cast<const u4*>(Zg + (((size_t)a3.z) << 11) + col0);
        u4 uB0 = *reinterpret_cast<const u4*>(Zg + (((size_t)b0.x) << 11) + col0);
        u4 uB1 = *reinterpret_cast<const u4*>(Zg + (((size_t)b0.z) << 11) + col0);
        u4 uB2 = *reinterpret_cast<const u4*>(Zg + (((size_t)b1.x) << 11) + col0);
        u4 uB3 = *reinterpret_cast<const u4*>(Zg + (((size_t)b1.z) << 11) + col0);
        u4 uB4 = *reinterpret_cast<const u4*>(Zg + (((size_t)b2.x) << 11) + col0);
        u4 uB5 = *reinterpret_cast<const u4*>(Zg + (((size_t)b2.z) << 11) + col0);
        u4 uB6 = *reinterpret_cast<const u4*>(Zg + (((size_t)b3.x) << 11) + col0);
        u4 uB7 = *reinterpret_cast<const u4*>(Zg + (((size_t)b3.z) << 11) + col0);
        f4 lo, hi;
        up8(uA0, lo, hi); aL0 += __int_as_float(a0.y) * lo; aH0 += __int_as_float(a0.y) * hi;
        up8(uA1, lo, hi); aL1 += __int_as_float(a0.w) * lo; aH1 += __int_as_float(a0.w) * hi;
        up8(uA2, lo, hi); aL0 += __int_as_float(a1.y) * lo; aH0 += __int_as_float(a1.y) * hi;
        up8(uA3, lo, hi); aL1 += __int_as_float(a1.w) * lo; aH1 += __int_as_float(a1.w) * hi;
        up8(uA4, lo, hi); aL0 += __int_as_float(a2.y) * lo; aH0 += __int_as_float(a2.y) * hi;
        up8(uA5, lo, hi); aL1 += __int_as_float(a2.w) * lo; aH1 += __int_as_float(a2.w) * hi;
        up8(uA6, lo, hi); aL0 += __int_as_float(a3.y) * lo; aH0 += __int_as_float(a3.y) * hi;
        up8(uA7, lo, hi); aL1 += __int_as_float(a3.w) * lo; aH1 += __int_as_float(a3.w) * hi;
        up8(uB0, lo, hi); bL0 += __int_as_float(b0.y) * lo; bH0 += __int_as_float(b0.y) * hi;
        up8(uB1, lo, hi); bL1 += __int_as_float(b0.w) * lo; bH1 += __int_as_float(b0.w) * hi;
        up8(uB2, lo, hi); bL0 += __int_as_float(b1.y) * lo; bH0 += __int_as_float(b1.y) * hi;
        up8(uB3, lo, hi); bL1 += __int_as_float(b1.w) * lo; bH1 += __int_as_float(b1.w) * hi;
        up8(uB4, lo, hi); bL0 += __int_as_float(b2.y) * lo; bH0 += __int_as_float(b2.y) * hi;
        up8(uB5, lo, hi); bL1 += __int_as_float(b2.w) * lo; bH1 += __int_as_float(b2.w) * hi;
        up8(uB6, lo, hi); bL0 += __int_as_float(b3.y) * lo; bH0 += __int_as_float(b3.y) * hi;
        up8(uB7, lo, hi); bL1 += __int_as_float(b3.w) * lo; bH1 += __int_as_float(b3.w) * hi;
    }

    size_t oA = (((size_t)nA) << 11) + col0;
    size_t oB = (((size_t)nB) << 11) + col0;
    f4 tAL = aL0 + aL1, tAH = aH0 + aH1;
    f4 tBL = bL0 + bL1, tBH = bH0 + bH1;
    if (Pown) {
        u4 puA = *reinterpret_cast<const u4*>(Pown + oA);
        u4 puB = *reinterpret_cast<const u4*>(Pown + oB);
        f4 pL, pH;
        up8(puA, pL, pH);
        tAL = 2.f * tAL - pL;
        tAH = 2.f * tAH - pH;
        up8(puB, pL, pH);
        tBL = 2.f * tBL - pL;
        tBH = 2.f * tBH - pH;
    }
    u4 stA, stB;
    stA.x = bfpk(tAL.x, tAL.y); stA.y = bfpk(tAL.z, tAL.w);
    stA.z = bfpk(tAH.x, tAH.y); stA.w = bfpk(tAH.z, tAH.w);
    stB.x = bfpk(tBL.x, tBL.y); stB.y = bfpk(tBL.z, tBL.w);
    stB.z = bfpk(tBH.x, tBH.y); stB.w = bfpk(tBH.z, tBH.w);
    *reinterpret_cast<u4*>(Tout + oA) = stA;
    *reinterpret_cast<u4*>(Tout + oB) = stB;
}

// ---------------------------------------------------------------------------
// Chebyshev finalizer, register-direct MFMA, PERMUTED layout (R14 form):
// gather & own-rows at plain lane*8; loaded 8 elements ARE the MFMA data
// fragment (b=lane&15, ci=(lane>>4)*8+j). Own-row loads hoisted.
// A = weights (row=co), B = data (col=batch); D[co][batch].
// ---------------------------------------------------------------------------
template <int COUT>
__global__ __launch_bounds__(256, 4) void k_cheb_mfma(
    const int* __restrict__ rowptr, const int2* __restrict__ cv,
    const ushort_t* __restrict__ T2g,  // gather source (T2), also own-row read
    const ushort_t* __restrict__ T1,   // own-row: Pown + W1 operand
    const ushort_t* __restrict__ H,    // own-row: W0 operand
    const uint_t* __restrict__ Wb,     // [4][32co][16] bf16-pair fragments
    const float* __restrict__ bias,    // [COUT]
    void* __restrict__ OUTv)
{
    int chunk = blockIdx.x & 3;
    int rowblk = blockIdx.x >> 2;
    int wave = threadIdx.x >> 6;
    int lane = threadIdx.x & 63;
    int n = rowblk * 4 + wave;
    int b16 = lane & 15, qk = lane >> 4;
    int col0 = chunk * 512 + lane * 8;
    size_t o = (((size_t)n) << 11) + col0;

    // hoisted own-row loads: latency overlaps the gather loop
    u4 a1 = *reinterpret_cast<const u4*>(T1 + o);
    u4 a2 = *reinterpret_cast<const u4*>(T2g + o);
    u4 a0 = *reinterpret_cast<const u4*>(H + o);

    int start = rowptr[n], end = rowptr[n + 1];
    f4 aL0 = {0,0,0,0}, aH0 = {0,0,0,0}, aL1 = {0,0,0,0}, aH1 = {0,0,0,0};
    for (int e = start; e < end; e += 8) {
        const int4* q = reinterpret_cast<const int4*>(cv + e);
        int4 a = q[0], b = q[1], c = q[2], d = q[3];
        u4 u0 = *reinterpret_cast<const u4*>(T2g + (((size_t)a.x) << 11) + col0);
        u4 u1 = *reinterpret_cast<const u4*>(T2g + (((size_t)a.z) << 11) + col0);
        u4 u2 = *reinterpret_cast<const u4*>(T2g + (((size_t)b.x) << 11) + col0);
        u4 u3 = *reinterpret_cast<const u4*>(T2g + (((size_t)b.z) << 11) + col0);
        u4 u4_ = *reinterpret_cast<const u4*>(T2g + (((size_t)c.x) << 11) + col0);
        u4 u5 = *reinterpret_cast<const u4*>(T2g + (((size_t)c.z) << 11) + col0);
        u4 u6 = *reinterpret_cast<const u4*>(T2g + (((size_t)d.x) << 11) + col0);
        u4 u7 = *reinterpret_cast<const u4*>(T2g + (((size_t)d.z) << 11) + col0);
        f4 lo, hi;
        up8(u0, lo, hi);  aL0 += __int_as_float(a.y) * lo; aH0 += __int_as_float(a.y) * hi;
        up8(u1, lo, hi);  aL1 += __int_as_float(a.w) * lo; aH1 += __int_as_float(a.w) * hi;
        up8(u2, lo, hi);  aL0 += __int_as_float(b.y) * lo; aH0 += __int_as_float(b.y) * hi;
        up8(u3, lo, hi);  aL1 += __int_as_float(b.w) * lo; aH1 += __int_as_float(b.w) * hi;
        up8(u4_, lo, hi); aL0 += __int_as_float(c.y) * lo; aH0 += __int_as_float(c.y) * hi;
        up8(u5, lo, hi);  aL1 += __int_as_float(c.w) * lo; aH1 += __int_as_float(c.w) * hi;
        up8(u6, lo, hi);  aL0 += __int_as_float(d.y) * lo; aH0 += __int_as_float(d.y) * hi;
        up8(u7, lo, hi);  aL1 += __int_as_float(d.w) * lo; aH1 += __int_as_float(d.w) * hi;
    }

    // T3 = 2*(L@T2) - T1 (bf16-packed, same permuted fragment positions)
    u4 a3;
    {
        f4 pL, pH;
        up8(a1, pL, pH);
        f4 tL = 2.f * (aL0 + aL1) - pL;
        f4 tH = 2.f * (aH0 + aH1) - pH;
        a3.x = bfpk(tL.x, tL.y); a3.y = bfpk(tL.z, tL.w);
        a3.z = bfpk(tH.x, tH.y); a3.w = bfpk(tH.z, tH.w);
    }

    // A-fragments (weights) from pre-packed global (L2-hot, 8KB)
    const uint_t* wb = Wb + b16 * 16 + qk * 4;
    f4 accA = {0,0,0,0}, accB = {0,0,0,0};
#pragma unroll
    for (int kk = 0; kk < 4; ++kk) {
        u4 af4 = (kk == 0) ? a0 : (kk == 1) ? a1 : (kk == 2) ? a2 : a3;
        bf16x8 bf_data = *reinterpret_cast<bf16x8*>(&af4);
        u4 w0 = *reinterpret_cast<const u4*>(wb + kk * 512);
        bf16x8 af_w0 = *reinterpret_cast<bf16x8*>(&w0);
        accA = __builtin_amdgcn_mfma_f32_16x16x32_bf16(af_w0, bf_data, accA, 0, 0, 0);
        if constexpr (COUT == 32) {
            u4 w1 = *reinterpret_cast<const u4*>(wb + kk * 512 + 256);
            bf16x8 af_w1 = *reinterpret_cast<bf16x8*>(&w1);
            accB = __builtin_amdgcn_mfma_f32_16x16x32_bf16(af_w1, bf_data, accB, 0, 0, 0);
        }
    }

    if constexpr (COUT == 32) {
        f4 bA = *reinterpret_cast<const f4*>(bias + qk * 4);
        f4 bB = *reinterpret_cast<const f4*>(bias + 16 + qk * 4);
        f4 vA = accA + bA, vB = accB + bB;
        vA.x = vA.x > 0.f ? vA.x : 0.f; vA.y = vA.y > 0.f ? vA.y : 0.f;
        vA.z = vA.z > 0.f ? vA.z : 0.f; vA.w = vA.w > 0.f ? vA.w : 0.f;
        vB.x = vB.x > 0.f ? vB.x : 0.f; vB.y = vB.y > 0.f ? vB.y : 0.f;
        vB.z = vB.z > 0.f ? vB.z : 0.f; vB.w = vB.w > 0.f ? vB.w : 0.f;
        ushort_t* OB = (ushort_t*)OUTv;
        int sA = 8 * b16 + ((qk >> 1) << 7) + ((qk & 1) << 2);
        size_t obase = (((size_t)n) << 11) + chunk * 512;
        u2 pA, pB;
        pA.x = bfpk(vA.x, vA.y); pA.y = bfpk(vA.z, vA.w);
        pB.x = bfpk(vB.x, vB.y); pB.y = bfpk(vB.z, vB.w);
        *reinterpret_cast<u2*>(OB + obase + sA) = pA;
        *reinterpret_cast<u2*>(OB + obase + sA + 256) = pB;
    } else {  // COUT == 4: logical fp32 out [N][256]; qk==0 holds co 0..3
        if (qk == 0) {
            f4 bA = *reinterpret_cast<const f4*>(bias);
            f4 vA = accA + bA;
            vA.x = vA.x > 0.f ? vA.x : 0.f; vA.y = vA.y > 0.f ? vA.y : 0.f;
            vA.z = vA.z > 0.f ? vA.z : 0.f; vA.w = vA.w > 0.f ? vA.w : 0.f;
            float* OF = (float*)OUTv;
            *reinterpret_cast<f4*>(OF + (size_t)n * 256 + chunk * 64 + b16 * 4) = vA;
        }
    }
}

// ---------------------------------------------------------------------------
// FC1: split-K over 128 blocks, atomic accumulate. h[b, n*4+c] = H5[n, b*4+c]
// ---------------------------------------------------------------------------
__global__ __launch_bounds__(256) void k_fc1(const float* __restrict__ H5,
                                             const float* __restrict__ fw1,
                                             float* __restrict__ fc1out) {
    __shared__ float hT[128 * 65];
    __shared__ float wS[32 * 128];
    int tid = threadIdx.x;
    int n0 = blockIdx.x * 32;
    for (int idx = tid; idx < 8192; idx += 256) {
        int n_l = idx >> 8;
        int rem = idx & 255;
        int b = rem >> 2, c = rem & 3;
        int kk = n_l * 4 + c;
        hT[kk * 65 + b] = H5[(size_t)(n0 + n_l) * 256 + rem];
    }
    float acc[8][4];
#pragma unroll
    for (int i = 0; i < 8; ++i)
#pragma unroll
        for (int j = 0; j < 4; ++j) acc[i][j] = 0.f;
    int bq = tid >> 5;
    int jq = tid & 31;
    for (int kb = 0; kb < 128; kb += 32) {
        __syncthreads();
        for (int idx = tid; idx < 4096; idx += 256) {
            int kl = idx >> 7, j = idx & 127;
            wS[idx] = fw1[(size_t)(n0 * 4 + kb + kl) * 128 + j];
        }
        __syncthreads();
        for (int kl = 0; kl < 32; ++kl) {
            int kk = kb + kl;
            float4 w = *reinterpret_cast<const float4*>(&wS[kl * 128 + jq * 4]);
#pragma unroll
            for (int bi = 0; bi < 8; ++bi) {
                float h = hT[kk * 65 + bq * 8 + bi];
                acc[bi][0] += h * w.x;
                acc[bi][1] += h * w.y;
                acc[bi][2] += h * w.z;
                acc[bi][3] += h * w.w;
            }
        }
    }
#pragma unroll
    for (int bi = 0; bi < 8; ++bi)
#pragma unroll
        for (int ji = 0; ji < 4; ++ji)
            atomicAdd(&fc1out[(bq * 8 + bi) * 128 + jq * 4 + ji], acc[bi][ji]);
}

__global__ __launch_bounds__(128) void k_fc23(const float* __restrict__ fc1out,
                                              const float* __restrict__ fb1,
                                              const float* __restrict__ fw2,
                                              const float* __restrict__ fb2,
                                              const float* __restrict__ fw3,
                                              const float* __restrict__ fb3,
                                              float* __restrict__ out) {
    int b = blockIdx.x;
    int j = threadIdx.x;
    __shared__ float r[128];
    __shared__ float s1[128];
    r[j] = fc1out[b * 128 + j] + fb1[j];
    __syncthreads();
    float acc = fb2[j];
    for (int i = 0; i < 128; ++i) acc += r[i] * fw2[i * 128 + j];
    s1[j] = acc;
    __syncthreads();
    if (j < 9) {
        float a2 = fb3[j];
        for (int i = 0; i < 128; ++i) a2 += s1[i] * fw3[i * 9 + j];
        out[b * 9 + j] = a2;
    }
}

// ---------------------------------------------------------------------------
extern "C" void kernel_launch(void* const* d_in, const int* in_sizes, int n_in,
                              void* d_out, int out_size, void* d_ws, size_t ws_size,
                              hipStream_t stream) {
    const float* x   = (const float*)d_in[0];
    const int*   src = (const int*)d_in[1];
    const int*   dst = (const int*)d_in[2];
    const float* ew  = (const float*)d_in[3];
    const float* w1  = (const float*)d_in[4];
    const float* b1  = (const float*)d_in[5];
    const float* w2  = (const float*)d_in[6];
    const float* b2  = (const float*)d_in[7];
    const float* w3  = (const float*)d_in[8];
    const float* b3  = (const float*)d_in[9];
    const float* w4  = (const float*)d_in[10];
    const float* b4  = (const float*)d_in[11];
    const float* w5  = (const float*)d_in[12];
    const float* b5  = (const float*)d_in[13];
    const float* fw1 = (const float*)d_in[14];
    const float* fb1 = (const float*)d_in[15];
    const float* fw2 = (const float*)d_in[16];
    const float* fb2 = (const float*)d_in[17];
    const float* fw3 = (const float*)d_in[18];
    const float* fb3 = (const float*)d_in[19];
    float* out = (float*)d_out;

    char* p = (char*)d_ws;
    const size_t XBYTES = (size_t)NN * 2048 * 2;  // 16 MB (bf16)
    ushort_t* X0 = (ushort_t*)(p + 0 * XBYTES);
    ushort_t* X1 = (ushort_t*)(p + 1 * XBYTES);
    ushort_t* X2 = (ushort_t*)(p + 2 * XBYTES);
    ushort_t* X3 = (ushort_t*)(p + 3 * XBYTES);
    size_t off = 4 * XBYTES;
    float* H5     = (float*)(p + off); off += (size_t)NN * 256 * 4;  // fp32
    float* deg    = (float*)(p + off); off += (size_t)NN * 4;
    int*   cnt    = (int*)(p + off);   off += (size_t)NN * 4;
    int*   cursor = (int*)(p + off);   off += (size_t)NN * 4;
    int*   rowptr = (int*)(p + off);   off += (size_t)(NN + 4) * 4;
    int2*  cv     = (int2*)(p + off);  off += (size_t)(EPAD + 8) * 8;  // +8 zero edges
    float* fc1o   = (float*)(p + off); off += (size_t)BB * 128 * 4;
    float* xn0    = (float*)(p + off); off += (size_t)NN * 64 * 4;
    float* tn1    = (float*)(p + off); off += (size_t)NN * 64 * 4;
    float* tn2    = (float*)(p + off); off += (size_t)NN * 64 * 4;
    float* tn3    = (float*)(p + off); off += (size_t)NN * 64 * 4;
    uint_t* Wb    = (uint_t*)(p + off); off += (size_t)4 * 2048 * 4;
    if (off > ws_size) return;

    hipMemsetAsync(deg, 0, NN * 4, stream);
    hipMemsetAsync(cnt, 0, NN * 4, stream);
    hipMemsetAsync(cv, 0, (size_t)(EPAD + 8) * 8, stream);
    hipMemsetAsync(fc1o, 0, BB * 128 * 4, stream);

    k_deg_hist<<<EE / 256, 256, 0, stream>>>(src, dst, ew, deg, cnt);
    k_scan<<<1, 1024, 0, stream>>>(cnt, rowptr, cursor);
    k_fill<<<EE / 256, 256, 0, stream>>>(src, dst, ew, deg, cursor, cv);
    k_packw<<<32, 256, 0, stream>>>(w2, w3, w4, w5, Wb);
    k_transpose_x<<<NN / 64, 256, 0, stream>>>(x, xn0);

    // ------------------- layer 1 entirely narrow fp32, then one bf16 expand
    k_spmm_narrow<<<NN, 64, 0, stream>>>(rowptr, cv, xn0, nullptr, tn1, 1.f, 0);
    k_spmm_narrow<<<NN, 64, 0, stream>>>(rowptr, cv, tn1, xn0, tn2, 2.f, 1);
    k_spmm_narrow<<<NN, 64, 0, stream>>>(rowptr, cv, tn2, tn1, tn3, 2.f, 1);
    k_expand1<<<NN, 256, 0, stream>>>(xn0, tn1, tn2, tn3, w1, b1, X3);  // H1 -> X3

    const int GRIDP = (NN / 8) * 4;   // 2048 blocks: 2 rows/wave
    const int GRIDC = (NN / 4) * 4;   // 4096 blocks
    // ------------------- layers 2-4: S1, S2 pure; S3 fused MFMA finalizer
    auto run32 = [&](const ushort_t* H, ushort_t* T1, ushort_t* T2, ushort_t* OUT,
                     const uint_t* WbL, const float* B) {
        k_spmm_pure<<<GRIDP, 256, 0, stream>>>(rowptr, cv, H, nullptr, T1);
        k_spmm_pure<<<GRIDP, 256, 0, stream>>>(rowptr, cv, T1, H, T2);
        k_cheb_mfma<32><<<GRIDC, 256, 0, stream>>>(rowptr, cv, T2, T1, H, WbL, B, OUT);
    };
    run32(X3, X0, X1, X2, Wb + 0 * 2048, b2);
    run32(X2, X3, X0, X1, Wb + 1 * 2048, b3);
    run32(X1, X2, X3, X0, Wb + 2 * 2048, b4);

    // ------------------- layer 5 (COUT=4): H=X0 -> H5 fp32 [N][256]
    k_spmm_pure<<<GRIDP, 256, 0, stream>>>(rowptr, cv, X0, nullptr, X1);
    k_spmm_pure<<<GRIDP, 256, 0, stream>>>(rowptr, cv, X1, X0, X2);
    k_cheb_mfma<4><<<GRIDC, 256, 0, stream>>>(rowptr, cv, X2, X1, X0, Wb + 3 * 2048, b5, H5);

    // ------------------- FC head
    k_fc1<<<128, 256, 0, stream>>>(H5, fw1, fc1o);
    k_fc23<<<BB, 128, 0, stream>>>(fc1o, fb1, fw2, fb2, fw3, fb3, out);
}

// Round 17
// 570.762 us; speedup vs baseline: 1.0894x; 1.0323x over previous
//
#include <hip/hip_runtime.h>
#include <cstdint>

#define NN 4096
#define EE 131072
#define BB 64
#define EPAD (EE + 8 * NN)   // CSR rows padded to multiples of 8

typedef float f4 __attribute__((ext_vector_type(4)));
typedef short bf16x8 __attribute__((ext_vector_type(8)));
typedef unsigned int u4 __attribute__((ext_vector_type(4)));
typedef unsigned int u2 __attribute__((ext_vector_type(2)));
typedef unsigned short ushort_t;
typedef unsigned int uint_t;

// bf16 helpers
__device__ __forceinline__ void up8(u4 u, f4& lo, f4& hi) {
    lo.x = __uint_as_float(u.x << 16);
    lo.y = __uint_as_float(u.x & 0xffff0000u);
    lo.z = __uint_as_float(u.y << 16);
    lo.w = __uint_as_float(u.y & 0xffff0000u);
    hi.x = __uint_as_float(u.z << 16);
    hi.y = __uint_as_float(u.z & 0xffff0000u);
    hi.z = __uint_as_float(u.w << 16);
    hi.w = __uint_as_float(u.w & 0xffff0000u);
}
__device__ __forceinline__ uint_t bfpk(float a, float b) {
    uint_t xa = __float_as_uint(a); xa = (xa + 0x7fffu + ((xa >> 16) & 1u)) >> 16;
    uint_t xb = __float_as_uint(b); xb = (xb + 0x7fffu + ((xb >> 16) & 1u));
    return (xa & 0xffffu) | (xb & 0xffff0000u);
}

// PERMUTED wide layout (per 512-col chunk): storage s(b,c) = 8b + 128*(c>>3) + (c&7)
// for local batch b in [0,16), channel c in [0,32). Element-wise kernels
// (spmm_pure) are layout-transparent; cheb gathers at lane*8 and the 8 loaded
// elements ARE the MFMA data fragment (b = lane&15, ci = (lane>>4)*8 + j).

// ---------------------------------------------------------------------------
// Graph preprocessing
// ---------------------------------------------------------------------------
__global__ void k_deg_hist(const int* __restrict__ src, const int* __restrict__ dst,
                           const float* __restrict__ ew, float* __restrict__ deg,
                           int* __restrict__ cnt) {
    int e = blockIdx.x * blockDim.x + threadIdx.x;
    if (e >= EE) return;
    atomicAdd(&deg[src[e]], ew[e]);
    atomicAdd(&cnt[dst[e]], 1);
}

__global__ __launch_bounds__(1024) void k_scan(const int* __restrict__ cnt,
                                               int* __restrict__ rowptr,
                                               int* __restrict__ cursor) {
    __shared__ int s[1024];
    int tid = threadIdx.x;
    int p0 = (cnt[tid * 4 + 0] + 7) & ~7;
    int p1 = (cnt[tid * 4 + 1] + 7) & ~7;
    int p2 = (cnt[tid * 4 + 2] + 7) & ~7;
    int p3 = (cnt[tid * 4 + 3] + 7) & ~7;
    int sum = p0 + p1 + p2 + p3;
    s[tid] = sum;
    __syncthreads();
    for (int off = 1; off < 1024; off <<= 1) {
        int t = (tid >= off) ? s[tid - off] : 0;
        __syncthreads();
        s[tid] += t;
        __syncthreads();
    }
    int excl = s[tid] - sum;
    rowptr[tid * 4 + 0] = excl; cursor[tid * 4 + 0] = excl; excl += p0;
    rowptr[tid * 4 + 1] = excl; cursor[tid * 4 + 1] = excl; excl += p1;
    rowptr[tid * 4 + 2] = excl; cursor[tid * 4 + 2] = excl; excl += p2;
    rowptr[tid * 4 + 3] = excl; cursor[tid * 4 + 3] = excl; excl += p3;
    if (tid == 1023) rowptr[4096] = excl;
}

__global__ void k_fill(const int* __restrict__ src, const int* __restrict__ dst,
                       const float* __restrict__ ew, const float* __restrict__ deg,
                       int* __restrict__ cursor, int2* __restrict__ cv) {
    int e = blockIdx.x * blockDim.x + threadIdx.x;
    if (e >= EE) return;
    int s = src[e], d = dst[e];
    int pos = atomicAdd(&cursor[d], 1);
    float ds = deg[s], dd = deg[d];
    float is = ds > 0.f ? rsqrtf(fmaxf(ds, 1e-30f)) : 0.f;
    float id = dd > 0.f ? rsqrtf(fmaxf(dd, 1e-30f)) : 0.f;
    float v = -(is * ew[e] * id);
    cv[pos] = make_int2(s, __float_as_int(v));
}

// ---------------------------------------------------------------------------
// One-time weight pre-pack into MFMA fragment order (bf16 pairs):
// Wb[L][kk*512 + co*16 + u] = (W_L[kk][2u][co], W_L[kk][2u+1][co])
// ---------------------------------------------------------------------------
__global__ __launch_bounds__(256) void k_packw(const float* __restrict__ w2,
                                               const float* __restrict__ w3,
                                               const float* __restrict__ w4,
                                               const float* __restrict__ w5,
                                               uint_t* __restrict__ Wb) {
    int idx = blockIdx.x * 256 + threadIdx.x;  // 0..8191
    int L = idx >> 11, rem = idx & 2047;
    int kk = rem >> 9, r2 = rem & 511, co = r2 >> 4, u = r2 & 15;
    float lo, hi;
    if (L < 3) {
        const float* W = (L == 0) ? w2 : (L == 1) ? w3 : w4;
        lo = W[kk * 1024 + (2 * u) * 32 + co];
        hi = W[kk * 1024 + (2 * u + 1) * 32 + co];
    } else {
        lo = (co < 4) ? w5[kk * 128 + (2 * u) * 4 + co] : 0.f;
        hi = (co < 4) ? w5[kk * 128 + (2 * u + 1) * 4 + co] : 0.f;
    }
    Wb[idx] = bfpk(lo, hi);
}

// ---------------------------------------------------------------------------
// Transpose x [B,N] -> X0 [N,B]  (fp32, layer-1 narrow path)
// ---------------------------------------------------------------------------
__global__ __launch_bounds__(256) void k_transpose_x(const float* __restrict__ x,
                                                     float* __restrict__ X0) {
    __shared__ float s[64 * 65];
    int n0 = blockIdx.x * 64;
    for (int idx = threadIdx.x; idx < 4096; idx += 256) {
        int b = idx >> 6, nl = idx & 63;
        s[nl * 65 + b] = x[(size_t)b * NN + n0 + nl];
    }
    __syncthreads();
    for (int idx = threadIdx.x; idx < 4096; idx += 256) {
        int nl = idx >> 6, b = idx & 63;
        X0[(size_t)(n0 + nl) * 64 + b] = s[nl * 65 + b];
    }
}

// ---------------------------------------------------------------------------
// SpMM narrow (width 64, fp32, layer 1), tail-free x8 gather loop
// ---------------------------------------------------------------------------
__global__ __launch_bounds__(64) void k_spmm_narrow(const int* __restrict__ rowptr,
                                                    const int2* __restrict__ cv,
                                                    const float* __restrict__ Zin,
                                                    const float* __restrict__ Tprev,
                                                    float* __restrict__ Tout,
                                                    float alpha, int useprev) {
    int n = blockIdx.x;
    int lane = threadIdx.x;
    int start = rowptr[n], end = rowptr[n + 1];
    float acc = 0.f;
    for (int e = start; e < end; e += 8) {
        const int4* q = reinterpret_cast<const int4*>(cv + e);
        int4 a = q[0], b = q[1], c = q[2], d = q[3];
        float z0 = Zin[((size_t)a.x << 6) + lane];
        float z1 = Zin[((size_t)a.z << 6) + lane];
        float z2 = Zin[((size_t)b.x << 6) + lane];
        float z3 = Zin[((size_t)b.z << 6) + lane];
        float z4 = Zin[((size_t)c.x << 6) + lane];
        float z5 = Zin[((size_t)c.z << 6) + lane];
        float z6 = Zin[((size_t)d.x << 6) + lane];
        float z7 = Zin[((size_t)d.z << 6) + lane];
        acc += __int_as_float(a.y) * z0 + __int_as_float(a.w) * z1
             + __int_as_float(b.y) * z2 + __int_as_float(b.w) * z3
             + __int_as_float(c.y) * z4 + __int_as_float(c.w) * z5
             + __int_as_float(d.y) * z6 + __int_as_float(d.w) * z7;
    }
    size_t o = ((size_t)n << 6) + lane;
    float r = alpha * acc;
    if (useprev) r -= Tprev[o];
    Tout[o] = r;
}

// ---------------------------------------------------------------------------
// Layer-1 expand -> bf16 H, PERMUTED layout.
// ---------------------------------------------------------------------------
__global__ __launch_bounds__(256) void k_expand1(const float* __restrict__ T0,
                                                 const float* __restrict__ T1,
                                                 const float* __restrict__ T2,
                                                 const float* __restrict__ T3,
                                                 const float* __restrict__ w1,
                                                 const float* __restrict__ b1,
                                                 ushort_t* __restrict__ H) {
    __shared__ float sT[4][64];
    __shared__ float sW[128];
    __shared__ float sB[32];
    int n = blockIdx.x, tid = threadIdx.x;
    {
        int k = tid >> 6, b = tid & 63;
        const float* Tk = (k == 0) ? T0 : (k == 1) ? T1 : (k == 2) ? T2 : T3;
        sT[k][b] = Tk[(size_t)n * 64 + b];
    }
    if (tid < 128) sW[tid] = w1[tid];
    if (tid < 32) sB[tid] = b1[tid];
    __syncthreads();
    int chunk = tid >> 6, blk = tid & 63;
    int b_g = chunk * 16 + (blk & 15);
    int co0 = (blk >> 4) * 8;
    float t0 = sT[0][b_g], t1 = sT[1][b_g], t2 = sT[2][b_g], t3 = sT[3][b_g];
    float r[8];
#pragma unroll
    for (int j = 0; j < 8; ++j) {
        int co = co0 + j;
        float v = t0 * sW[co] + t1 * sW[32 + co] + t2 * sW[64 + co] + t3 * sW[96 + co] + sB[co];
        r[j] = v > 0.f ? v : 0.f;
    }
    u4 st;
    st.x = bfpk(r[0], r[1]); st.y = bfpk(r[2], r[3]);
    st.z = bfpk(r[4], r[5]); st.w = bfpk(r[6], r[7]);
    *reinterpret_cast<u4*>(H + (size_t)n * 2048 + tid * 8) = st;
}

// ---------------------------------------------------------------------------
// Pure wide SpMM (bf16, fp32 accumulate), 4 chunks x 512 cols, 16B gathers.
// One row per wave (R14 form — best measured).
// ---------------------------------------------------------------------------
__global__ __launch_bounds__(256, 4) void k_spmm_pure(const int* __restrict__ rowptr,
                                                      const int2* __restrict__ cv,
                                                      const ushort_t* __restrict__ Zg,
                                                      const ushort_t* __restrict__ Pown,
                                                      ushort_t* __restrict__ Tout) {
    int chunk = blockIdx.x & 3;
    int rowblk = blockIdx.x >> 2;
    int wave = threadIdx.x >> 6;
    int lane = threadIdx.x & 63;
    int n = rowblk * 4 + wave;
    int col0 = chunk * 512 + lane * 8;

    int start = rowptr[n], end = rowptr[n + 1];
    f4 aL0 = {0,0,0,0}, aH0 = {0,0,0,0}, aL1 = {0,0,0,0}, aH1 = {0,0,0,0};
    for (int e = start; e < end; e += 8) {
        const int4* q = reinterpret_cast<const int4*>(cv + e);
        int4 a = q[0], b = q[1], c = q[2], d = q[3];
        u4 u0 = *reinterpret_cast<const u4*>(Zg + (((size_t)a.x) << 11) + col0);
        u4 u1 = *reinterpret_cast<const u4*>(Zg + (((size_t)a.z) << 11) + col0);
        u4 u2 = *reinterpret_cast<const u4*>(Zg + (((size_t)b.x) << 11) + col0);
        u4 u3 = *reinterpret_cast<const u4*>(Zg + (((size_t)b.z) << 11) + col0);
        u4 u4_ = *reinterpret_cast<const u4*>(Zg + (((size_t)c.x) << 11) + col0);
        u4 u5 = *reinterpret_cast<const u4*>(Zg + (((size_t)c.z) << 11) + col0);
        u4 u6 = *reinterpret_cast<const u4*>(Zg + (((size_t)d.x) << 11) + col0);
        u4 u7 = *reinterpret_cast<const u4*>(Zg + (((size_t)d.z) << 11) + col0);
        f4 lo, hi;
        up8(u0, lo, hi);  aL0 += __int_as_float(a.y) * lo; aH0 += __int_as_float(a.y) * hi;
        up8(u1, lo, hi);  aL1 += __int_as_float(a.w) * lo; aH1 += __int_as_float(a.w) * hi;
        up8(u2, lo, hi);  aL0 += __int_as_float(b.y) * lo; aH0 += __int_as_float(b.y) * hi;
        up8(u3, lo, hi);  aL1 += __int_as_float(b.w) * lo; aH1 += __int_as_float(b.w) * hi;
        up8(u4_, lo, hi); aL0 += __int_as_float(c.y) * lo; aH0 += __int_as_float(c.y) * hi;
        up8(u5, lo, hi);  aL1 += __int_as_float(c.w) * lo; aH1 += __int_as_float(c.w) * hi;
        up8(u6, lo, hi);  aL0 += __int_as_float(d.y) * lo; aH0 += __int_as_float(d.y) * hi;
        up8(u7, lo, hi);  aL1 += __int_as_float(d.w) * lo; aH1 += __int_as_float(d.w) * hi;
    }
    size_t o = (((size_t)n) << 11) + col0;
    f4 tL = aL0 + aL1, tH = aH0 + aH1;
    if (Pown) {
        u4 pu = *reinterpret_cast<const u4*>(Pown + o);
        f4 pL, pH;
        up8(pu, pL, pH);
        tL = 2.f * tL - pL;
        tH = 2.f * tH - pH;
    }
    u4 st;
    st.x = bfpk(tL.x, tL.y); st.y = bfpk(tL.z, tL.w);
    st.z = bfpk(tH.x, tH.y); st.w = bfpk(tH.z, tH.w);
    *reinterpret_cast<u4*>(Tout + o) = st;
}

// ---------------------------------------------------------------------------
// Chebyshev finalizer, register-direct MFMA, PERMUTED layout (R14 form)
// + weight fragments hoisted above the gather loop (latency hidden).
// ---------------------------------------------------------------------------
template <int COUT>
__global__ __launch_bounds__(256, 4) void k_cheb_mfma(
    const int* __restrict__ rowptr, const int2* __restrict__ cv,
    const ushort_t* __restrict__ T2g,  // gather source (T2), also own-row read
    const ushort_t* __restrict__ T1,   // own-row: Pown + W1 operand
    const ushort_t* __restrict__ H,    // own-row: W0 operand
    const uint_t* __restrict__ Wb,     // [4][32co][16] bf16-pair fragments
    const float* __restrict__ bias,    // [COUT]
    void* __restrict__ OUTv)
{
    int chunk = blockIdx.x & 3;
    int rowblk = blockIdx.x >> 2;
    int wave = threadIdx.x >> 6;
    int lane = threadIdx.x & 63;
    int n = rowblk * 4 + wave;
    int b16 = lane & 15, qk = lane >> 4;
    int col0 = chunk * 512 + lane * 8;
    size_t o = (((size_t)n) << 11) + col0;

    // hoisted loads: own-rows + weight fragments; latency overlaps the gather
    u4 a1 = *reinterpret_cast<const u4*>(T1 + o);
    u4 a2 = *reinterpret_cast<const u4*>(T2g + o);
    u4 a0 = *reinterpret_cast<const u4*>(H + o);
    const uint_t* wb = Wb + b16 * 16 + qk * 4;
    u4 wA0 = *reinterpret_cast<const u4*>(wb + 0 * 512);
    u4 wA1 = *reinterpret_cast<const u4*>(wb + 1 * 512);
    u4 wA2 = *reinterpret_cast<const u4*>(wb + 2 * 512);
    u4 wA3 = *reinterpret_cast<const u4*>(wb + 3 * 512);
    u4 wB0, wB1, wB2, wB3;
    if constexpr (COUT == 32) {
        wB0 = *reinterpret_cast<const u4*>(wb + 0 * 512 + 256);
        wB1 = *reinterpret_cast<const u4*>(wb + 1 * 512 + 256);
        wB2 = *reinterpret_cast<const u4*>(wb + 2 * 512 + 256);
        wB3 = *reinterpret_cast<const u4*>(wb + 3 * 512 + 256);
    }

    int start = rowptr[n], end = rowptr[n + 1];
    f4 aL0 = {0,0,0,0}, aH0 = {0,0,0,0}, aL1 = {0,0,0,0}, aH1 = {0,0,0,0};
    for (int e = start; e < end; e += 8) {
        const int4* q = reinterpret_cast<const int4*>(cv + e);
        int4 a = q[0], b = q[1], c = q[2], d = q[3];
        u4 u0 = *reinterpret_cast<const u4*>(T2g + (((size_t)a.x) << 11) + col0);
        u4 u1 = *reinterpret_cast<const u4*>(T2g + (((size_t)a.z) << 11) + col0);
        u4 u2 = *reinterpret_cast<const u4*>(T2g + (((size_t)b.x) << 11) + col0);
        u4 u3 = *reinterpret_cast<const u4*>(T2g + (((size_t)b.z) << 11) + col0);
        u4 u4_ = *reinterpret_cast<const u4*>(T2g + (((size_t)c.x) << 11) + col0);
        u4 u5 = *reinterpret_cast<const u4*>(T2g + (((size_t)c.z) << 11) + col0);
        u4 u6 = *reinterpret_cast<const u4*>(T2g + (((size_t)d.x) << 11) + col0);
        u4 u7 = *reinterpret_cast<const u4*>(T2g + (((size_t)d.z) << 11) + col0);
        f4 lo, hi;
        up8(u0, lo, hi);  aL0 += __int_as_float(a.y) * lo; aH0 += __int_as_float(a.y) * hi;
        up8(u1, lo, hi);  aL1 += __int_as_float(a.w) * lo; aH1 += __int_as_float(a.w) * hi;
        up8(u2, lo, hi);  aL0 += __int_as_float(b.y) * lo; aH0 += __int_as_float(b.y) * hi;
        up8(u3, lo, hi);  aL1 += __int_as_float(b.w) * lo; aH1 += __int_as_float(b.w) * hi;
        up8(u4_, lo, hi); aL0 += __int_as_float(c.y) * lo; aH0 += __int_as_float(c.y) * hi;
        up8(u5, lo, hi);  aL1 += __int_as_float(c.w) * lo; aH1 += __int_as_float(c.w) * hi;
        up8(u6, lo, hi);  aL0 += __int_as_float(d.y) * lo; aH0 += __int_as_float(d.y) * hi;
        up8(u7, lo, hi);  aL1 += __int_as_float(d.w) * lo; aH1 += __int_as_float(d.w) * hi;
    }

    // T3 = 2*(L@T2) - T1 (bf16-packed, same permuted fragment positions)
    u4 a3;
    {
        f4 pL, pH;
        up8(a1, pL, pH);
        f4 tL = 2.f * (aL0 + aL1) - pL;
        f4 tH = 2.f * (aH0 + aH1) - pH;
        a3.x = bfpk(tL.x, tL.y); a3.y = bfpk(tL.z, tL.w);
        a3.z = bfpk(tH.x, tH.y); a3.w = bfpk(tH.z, tH.w);
    }

    f4 accA = {0,0,0,0}, accB = {0,0,0,0};
#pragma unroll
    for (int kk = 0; kk < 4; ++kk) {
        u4 af4 = (kk == 0) ? a0 : (kk == 1) ? a1 : (kk == 2) ? a2 : a3;
        bf16x8 bf_data = *reinterpret_cast<bf16x8*>(&af4);
        u4 wA = (kk == 0) ? wA0 : (kk == 1) ? wA1 : (kk == 2) ? wA2 : wA3;
        bf16x8 af_w0 = *reinterpret_cast<bf16x8*>(&wA);
        accA = __builtin_amdgcn_mfma_f32_16x16x32_bf16(af_w0, bf_data, accA, 0, 0, 0);
        if constexpr (COUT == 32) {
            u4 wB = (kk == 0) ? wB0 : (kk == 1) ? wB1 : (kk == 2) ? wB2 : wB3;
            bf16x8 af_w1 = *reinterpret_cast<bf16x8*>(&wB);
            accB = __builtin_amdgcn_mfma_f32_16x16x32_bf16(af_w1, bf_data, accB, 0, 0, 0);
        }
    }

    if constexpr (COUT == 32) {
        f4 bA = *reinterpret_cast<const f4*>(bias + qk * 4);
        f4 bB = *reinterpret_cast<const f4*>(bias + 16 + qk * 4);
        f4 vA = accA + bA, vB = accB + bB;
        vA.x = vA.x > 0.f ? vA.x : 0.f; vA.y = vA.y > 0.f ? vA.y : 0.f;
        vA.z = vA.z > 0.f ? vA.z : 0.f; vA.w = vA.w > 0.f ? vA.w : 0.f;
        vB.x = vB.x > 0.f ? vB.x : 0.f; vB.y = vB.y > 0.f ? vB.y : 0.f;
        vB.z = vB.z > 0.f ? vB.z : 0.f; vB.w = vB.w > 0.f ? vB.w : 0.f;
        ushort_t* OB = (ushort_t*)OUTv;
        int sA = 8 * b16 + ((qk >> 1) << 7) + ((qk & 1) << 2);
        size_t obase = (((size_t)n) << 11) + chunk * 512;
        u2 pA, pB;
        pA.x = bfpk(vA.x, vA.y); pA.y = bfpk(vA.z, vA.w);
        pB.x = bfpk(vB.x, vB.y); pB.y = bfpk(vB.z, vB.w);
        *reinterpret_cast<u2*>(OB + obase + sA) = pA;
        *reinterpret_cast<u2*>(OB + obase + sA + 256) = pB;
    } else {  // COUT == 4: logical fp32 out [N][256]; qk==0 holds co 0..3
        if (qk == 0) {
            f4 bA = *reinterpret_cast<const f4*>(bias);
            f4 vA = accA + bA;
            vA.x = vA.x > 0.f ? vA.x : 0.f; vA.y = vA.y > 0.f ? vA.y : 0.f;
            vA.z = vA.z > 0.f ? vA.z : 0.f; vA.w = vA.w > 0.f ? vA.w : 0.f;
            float* OF = (float*)OUTv;
            *reinterpret_cast<f4*>(OF + (size_t)n * 256 + chunk * 64 + b16 * 4) = vA;
        }
    }
}

// ---------------------------------------------------------------------------
// FC1: split-K over 128 blocks, atomic accumulate. h[b, n*4+c] = H5[n, b*4+c]
// ---------------------------------------------------------------------------
__global__ __launch_bounds__(256) void k_fc1(const float* __restrict__ H5,
                                             const float* __restrict__ fw1,
                                             float* __restrict__ fc1out) {
    __shared__ float hT[128 * 65];
    __shared__ float wS[32 * 128];
    int tid = threadIdx.x;
    int n0 = blockIdx.x * 32;
    for (int idx = tid; idx < 8192; idx += 256) {
        int n_l = idx >> 8;
        int rem = idx & 255;
        int b = rem >> 2, c = rem & 3;
        int kk = n_l * 4 + c;
        hT[kk * 65 + b] = H5[(size_t)(n0 + n_l) * 256 + rem];
    }
    float acc[8][4];
#pragma unroll
    for (int i = 0; i < 8; ++i)
#pragma unroll
        for (int j = 0; j < 4; ++j) acc[i][j] = 0.f;
    int bq = tid >> 5;
    int jq = tid & 31;
    for (int kb = 0; kb < 128; kb += 32) {
        __syncthreads();
        for (int idx = tid; idx < 4096; idx += 256) {
            int kl = idx >> 7, j = idx & 127;
            wS[idx] = fw1[(size_t)(n0 * 4 + kb + kl) * 128 + j];
        }
        __syncthreads();
        for (int kl = 0; kl < 32; ++kl) {
            int kk = kb + kl;
            float4 w = *reinterpret_cast<const float4*>(&wS[kl * 128 + jq * 4]);
#pragma unroll
            for (int bi = 0; bi < 8; ++bi) {
                float h = hT[kk * 65 + bq * 8 + bi];
                acc[bi][0] += h * w.x;
                acc[bi][1] += h * w.y;
                acc[bi][2] += h * w.z;
                acc[bi][3] += h * w.w;
            }
        }
    }
#pragma unroll
    for (int bi = 0; bi < 8; ++bi)
#pragma unroll
        for (int ji = 0; ji < 4; ++ji)
            atomicAdd(&fc1out[(bq * 8 + bi) * 128 + jq * 4 + ji], acc[bi][ji]);
}

__global__ __launch_bounds__(128) void k_fc23(const float* __restrict__ fc1out,
                                              const float* __restrict__ fb1,
                                              const float* __restrict__ fw2,
                                              const float* __restrict__ fb2,
                                              const float* __restrict__ fw3,
                                              const float* __restrict__ fb3,
                                              float* __restrict__ out) {
    int b = blockIdx.x;
    int j = threadIdx.x;
    __shared__ float r[128];
    __shared__ float s1[128];
    r[j] = fc1out[b * 128 + j] + fb1[j];
    __syncthreads();
    float acc = fb2[j];
    for (int i = 0; i < 128; ++i) acc += r[i] * fw2[i * 128 + j];
    s1[j] = acc;
    __syncthreads();
    if (j < 9) {
        float a2 = fb3[j];
        for (int i = 0; i < 128; ++i) a2 += s1[i] * fw3[i * 9 + j];
        out[b * 9 + j] = a2;
    }
}

// ---------------------------------------------------------------------------
extern "C" void kernel_launch(void* const* d_in, const int* in_sizes, int n_in,
                              void* d_out, int out_size, void* d_ws, size_t ws_size,
                              hipStream_t stream) {
    const float* x   = (const float*)d_in[0];
    const int*   src = (const int*)d_in[1];
    const int*   dst = (const int*)d_in[2];
    const float* ew  = (const float*)d_in[3];
    const float* w1  = (const float*)d_in[4];
    const float* b1  = (const float*)d_in[5];
    const float* w2  = (const float*)d_in[6];
    const float* b2  = (const float*)d_in[7];
    const float* w3  = (const float*)d_in[8];
    const float* b3  = (const float*)d_in[9];
    const float* w4  = (const float*)d_in[10];
    const float* b4  = (const float*)d_in[11];
    const float* w5  = (const float*)d_in[12];
    const float* b5  = (const float*)d_in[13];
    const float* fw1 = (const float*)d_in[14];
    const float* fb1 = (const float*)d_in[15];
    const float* fw2 = (const float*)d_in[16];
    const float* fb2 = (const float*)d_in[17];
    const float* fw3 = (const float*)d_in[18];
    const float* fb3 = (const float*)d_in[19];
    float* out = (float*)d_out;

    char* p = (char*)d_ws;
    const size_t XBYTES = (size_t)NN * 2048 * 2;  // 16 MB (bf16)
    ushort_t* X0 = (ushort_t*)(p + 0 * XBYTES);
    ushort_t* X1 = (ushort_t*)(p + 1 * XBYTES);
    ushort_t* X2 = (ushort_t*)(p + 2 * XBYTES);
    ushort_t* X3 = (ushort_t*)(p + 3 * XBYTES);
    size_t off = 4 * XBYTES;
    float* H5     = (float*)(p + off); off += (size_t)NN * 256 * 4;  // fp32
    float* deg    = (float*)(p + off); off += (size_t)NN * 4;
    int*   cnt    = (int*)(p + off);   off += (size_t)NN * 4;
    int*   cursor = (int*)(p + off);   off += (size_t)NN * 4;
    int*   rowptr = (int*)(p + off);   off += (size_t)(NN + 4) * 4;
    int2*  cv     = (int2*)(p + off);  off += (size_t)EPAD * 8;
    float* fc1o   = (float*)(p + off); off += (size_t)BB * 128 * 4;
    float* xn0    = (float*)(p + off); off += (size_t)NN * 64 * 4;
    float* tn1    = (float*)(p + off); off += (size_t)NN * 64 * 4;
    float* tn2    = (float*)(p + off); off += (size_t)NN * 64 * 4;
    float* tn3    = (float*)(p + off); off += (size_t)NN * 64 * 4;
    uint_t* Wb    = (uint_t*)(p + off); off += (size_t)4 * 2048 * 4;
    if (off > ws_size) return;

    hipMemsetAsync(deg, 0, NN * 4, stream);
    hipMemsetAsync(cnt, 0, NN * 4, stream);
    hipMemsetAsync(cv, 0, (size_t)EPAD * 8, stream);
    hipMemsetAsync(fc1o, 0, BB * 128 * 4, stream);

    k_deg_hist<<<EE / 256, 256, 0, stream>>>(src, dst, ew, deg, cnt);
    k_scan<<<1, 1024, 0, stream>>>(cnt, rowptr, cursor);
    k_fill<<<EE / 256, 256, 0, stream>>>(src, dst, ew, deg, cursor, cv);
    k_packw<<<32, 256, 0, stream>>>(w2, w3, w4, w5, Wb);
    k_transpose_x<<<NN / 64, 256, 0, stream>>>(x, xn0);

    // ------------------- layer 1 entirely narrow fp32, then one bf16 expand
    k_spmm_narrow<<<NN, 64, 0, stream>>>(rowptr, cv, xn0, nullptr, tn1, 1.f, 0);
    k_spmm_narrow<<<NN, 64, 0, stream>>>(rowptr, cv, tn1, xn0, tn2, 2.f, 1);
    k_spmm_narrow<<<NN, 64, 0, stream>>>(rowptr, cv, tn2, tn1, tn3, 2.f, 1);
    k_expand1<<<NN, 256, 0, stream>>>(xn0, tn1, tn2, tn3, w1, b1, X3);  // H1 -> X3

    const int GRID4 = (NN / 4) * 4;   // 4096 blocks: 4 chunks x 512 cols
    // ------------------- layers 2-4: S1, S2 pure; S3 fused MFMA finalizer
    auto run32 = [&](const ushort_t* H, ushort_t* T1, ushort_t* T2, ushort_t* OUT,
                     const uint_t* WbL, const float* B) {
        k_spmm_pure<<<GRID4, 256, 0, stream>>>(rowptr, cv, H, nullptr, T1);
        k_spmm_pure<<<GRID4, 256, 0, stream>>>(rowptr, cv, T1, H, T2);
        k_cheb_mfma<32><<<GRID4, 256, 0, stream>>>(rowptr, cv, T2, T1, H, WbL, B, OUT);
    };
    run32(X3, X0, X1, X2, Wb + 0 * 2048, b2);
    run32(X2, X3, X0, X1, Wb + 1 * 2048, b3);
    run32(X1, X2, X3, X0, Wb + 2 * 2048, b4);

    // ------------------- layer 5 (COUT=4): H=X0 -> H5 fp32 [N][256]
    k_spmm_pure<<<GRID4, 256, 0, stream>>>(rowptr, cv, X0, nullptr, X1);
    k_spmm_pure<<<GRID4, 256, 0, stream>>>(rowptr, cv, X1, X0, X2);
    k_cheb_mfma<4><<<GRID4, 256, 0, stream>>>(rowptr, cv, X2, X1, X0, Wb + 3 * 2048, b5, H5);

    // ------------------- FC head
    k_fc1<<<128, 256, 0, stream>>>(H5, fw1, fc1o);
    k_fc23<<<BB, 128, 0, stream>>>(fc1o, fb1, fw2, fb2, fw3, fb3, out);
}